// Round 1
// baseline (1065.085 us; speedup 1.0000x reference)
//
#include <hip/hip_runtime.h>
#include <math.h>

#define BB 4
#define LL 2048
#define DD 512
#define KDIM 64
#define HH 8

// ---------------------------------------------------------------------------
// GEMM: Out[M,N] = X[M,K] @ ((W_int[K,N] - zp) * sc) + bias[N]
// BM=BN=64, BK=16, 256 threads, 4x4 microtile per thread.
// ---------------------------------------------------------------------------
__global__ __launch_bounds__(256)
void gemm_deq(const float* __restrict__ X, const int* __restrict__ W,
              const float* __restrict__ bias, const float* __restrict__ scp,
              const float* __restrict__ zpp, float* __restrict__ Out,
              int M, int N, int K)
{
    constexpr int BM = 64, BN = 64, BK = 16;
    __shared__ float As[BK][BM + 1];
    __shared__ float Bs[BK][BN + 1];
    const int tid = threadIdx.x;
    const int tx = tid & 15, ty = tid >> 4;
    const int rowBase = blockIdx.y * BM, colBase = blockIdx.x * BN;
    const float sc = *scp, zp = *zpp;
    float acc[4][4] = {};
    const int ar = tid >> 2, ak = (tid & 3) << 2;   // A-load: row, k-offset
    const int bk = tid >> 4, bc = (tid & 15) << 2;  // B-load: k, col-offset

    for (int kt = 0; kt < K; kt += BK) {
        float4 a4 = *(const float4*)(X + (size_t)(rowBase + ar) * K + kt + ak);
        As[ak + 0][ar] = a4.x; As[ak + 1][ar] = a4.y;
        As[ak + 2][ar] = a4.z; As[ak + 3][ar] = a4.w;
        int4 w4 = *(const int4*)(W + (size_t)(kt + bk) * N + colBase + bc);
        Bs[bk][bc + 0] = ((float)w4.x - zp) * sc;
        Bs[bk][bc + 1] = ((float)w4.y - zp) * sc;
        Bs[bk][bc + 2] = ((float)w4.z - zp) * sc;
        Bs[bk][bc + 3] = ((float)w4.w - zp) * sc;
        __syncthreads();
        #pragma unroll
        for (int kk = 0; kk < BK; ++kk) {
            float a[4], b[4];
            #pragma unroll
            for (int i = 0; i < 4; ++i) a[i] = As[kk][ty * 4 + i];
            #pragma unroll
            for (int j = 0; j < 4; ++j) b[j] = Bs[kk][tx * 4 + j];
            #pragma unroll
            for (int i = 0; i < 4; ++i)
                #pragma unroll
                for (int j = 0; j < 4; ++j)
                    acc[i][j] = fmaf(a[i], b[j], acc[i][j]);
        }
        __syncthreads();
    }
    #pragma unroll
    for (int i = 0; i < 4; ++i) {
        const int c0 = colBase + tx * 4;
        float4 o;
        o.x = acc[i][0] + bias[c0 + 0];
        o.y = acc[i][1] + bias[c0 + 1];
        o.z = acc[i][2] + bias[c0 + 2];
        o.w = acc[i][3] + bias[c0 + 3];
        *(float4*)(Out + (size_t)(rowBase + ty * 4 + i) * N + c0) = o;
    }
}

// ---------------------------------------------------------------------------
// Flash-style attention per (b, h, 64-row Q tile).
// Q/K/V live in plain (B*L, 512) layout, col = d*H + h  (== flat (B,L,KD,H)).
// O written in the same layout -> final GEMM consumes it directly.
// ---------------------------------------------------------------------------
__global__ __launch_bounds__(256)
void attn_kernel(const float* __restrict__ Q, const float* __restrict__ K,
                 const float* __restrict__ V, float* __restrict__ O)
{
    constexpr int QB = 64, KB = 64;
    __shared__ float q_s[KDIM][QB + 4];   // transposed: [d][row]
    __shared__ float k_s[KDIM][KB + 4];   // transposed: [d][key]
    __shared__ float v_s[KB][KDIM + 4];   // row-major:  [key][d]
    __shared__ float p_s[QB][KB + 1];
    __shared__ float row_m[QB], row_l[QB], row_f[QB];

    const int tid = threadIdx.x;
    const int tx = tid & 15, ty = tid >> 4;
    const int qb = blockIdx.x * QB;
    const int h  = blockIdx.y;
    const int b  = blockIdx.z;
    const float* Qb = Q + (size_t)b * LL * DD + h;
    const float* Kb = K + (size_t)b * LL * DD + h;
    const float* Vb = V + (size_t)b * LL * DD + h;

    for (int idx = tid; idx < QB * KDIM; idx += 256) {
        int r = idx >> 6, d = idx & 63;
        q_s[d][r] = Qb[(size_t)(qb + r) * DD + d * HH];
    }
    if (tid < QB) { row_m[tid] = -1e30f; row_l[tid] = 0.f; }
    float acc[4][4] = {};
    __syncthreads();

    for (int kb = 0; kb < LL; kb += KB) {
        for (int idx = tid; idx < KB * KDIM; idx += 256) {
            int r = idx >> 6, d = idx & 63;
            k_s[d][r] = Kb[(size_t)(kb + r) * DD + d * HH];
            v_s[r][d] = Vb[(size_t)(kb + r) * DD + d * HH];
        }
        __syncthreads();

        // --- scores: 4x4 microtile per thread ---
        float s[4][4] = {};
        for (int d = 0; d < KDIM; ++d) {
            float a[4];
            #pragma unroll
            for (int i = 0; i < 4; ++i) a[i] = q_s[d][ty * 4 + i];
            float4 b4 = *(const float4*)&k_s[d][tx * 4];
            #pragma unroll
            for (int i = 0; i < 4; ++i) {
                s[i][0] = fmaf(a[i], b4.x, s[i][0]);
                s[i][1] = fmaf(a[i], b4.y, s[i][1]);
                s[i][2] = fmaf(a[i], b4.z, s[i][2]);
                s[i][3] = fmaf(a[i], b4.w, s[i][3]);
            }
        }
        #pragma unroll
        for (int i = 0; i < 4; ++i)
            #pragma unroll
            for (int j = 0; j < 4; ++j)
                p_s[ty * 4 + i][tx * 4 + j] = s[i][j] * 0.125f;
        __syncthreads();

        // --- online softmax: 4 threads per row ---
        {
            const int r = tid >> 2, sub = tid & 3;
            float vals[16];
            float mloc = -1e30f;
            #pragma unroll
            for (int jj = 0; jj < 16; ++jj) {
                vals[jj] = p_s[r][sub * 16 + jj];
                mloc = fmaxf(mloc, vals[jj]);
            }
            mloc = fmaxf(mloc, __shfl_xor(mloc, 1));
            mloc = fmaxf(mloc, __shfl_xor(mloc, 2));
            const float mold = row_m[r];
            const float mnew = fmaxf(mold, mloc);
            float lloc = 0.f;
            #pragma unroll
            for (int jj = 0; jj < 16; ++jj) {
                float p = __expf(vals[jj] - mnew);
                lloc += p;
                p_s[r][sub * 16 + jj] = p;
            }
            lloc += __shfl_xor(lloc, 1);
            lloc += __shfl_xor(lloc, 2);
            if (sub == 0) {
                float f = __expf(mold - mnew);
                row_f[r] = f;
                row_m[r] = mnew;
                row_l[r] = row_l[r] * f + lloc;
            }
        }
        __syncthreads();

        // --- PV accumulate ---
        float f[4];
        #pragma unroll
        for (int i = 0; i < 4; ++i) f[i] = row_f[ty * 4 + i];
        #pragma unroll
        for (int i = 0; i < 4; ++i)
            #pragma unroll
            for (int j = 0; j < 4; ++j) acc[i][j] *= f[i];
        for (int j = 0; j < KB; ++j) {
            float p[4];
            #pragma unroll
            for (int i = 0; i < 4; ++i) p[i] = p_s[ty * 4 + i][j];
            float4 v4 = *(const float4*)&v_s[j][tx * 4];
            #pragma unroll
            for (int i = 0; i < 4; ++i) {
                acc[i][0] = fmaf(p[i], v4.x, acc[i][0]);
                acc[i][1] = fmaf(p[i], v4.y, acc[i][1]);
                acc[i][2] = fmaf(p[i], v4.z, acc[i][2]);
                acc[i][3] = fmaf(p[i], v4.w, acc[i][3]);
            }
        }
        __syncthreads();
    }

    // epilogue: normalize, write O in (B,L,KD,H) flat layout
    #pragma unroll
    for (int i = 0; i < 4; ++i) {
        float inv = 1.f / row_l[ty * 4 + i];
        #pragma unroll
        for (int j = 0; j < 4; ++j) {
            O[(size_t)(b * LL + qb + ty * 4 + i) * DD + (tx * 4 + j) * HH + h] =
                acc[i][j] * inv;
        }
    }
}

// ---------------------------------------------------------------------------
extern "C" void kernel_launch(void* const* d_in, const int* in_sizes, int n_in,
                              void* d_out, int out_size, void* d_ws, size_t ws_size,
                              hipStream_t stream)
{
    const float* query = (const float*)d_in[0];
    const float* key   = (const float*)d_in[1];
    const float* value = (const float*)d_in[2];
    const int* wq = (const int*)d_in[3];
    const int* wk = (const int*)d_in[4];
    const int* wv = (const int*)d_in[5];
    const int* wo = (const int*)d_in[6];
    const float* bq = (const float*)d_in[7];
    const float* bk = (const float*)d_in[8];
    const float* bv = (const float*)d_in[9];
    const float* bo = (const float*)d_in[10];
    const float* scale_q = (const float*)d_in[11];
    const float* scale_k = (const float*)d_in[12];
    const float* scale_v = (const float*)d_in[13];
    const float* scale_o = (const float*)d_in[14];
    const float* zp_q = (const float*)d_in[15];
    const float* zp_k = (const float*)d_in[16];
    const float* zp_v = (const float*)d_in[17];
    const float* zp_o = (const float*)d_in[18];

    const int M = BB * LL;   // 8192
    const int N = DD;        // 512
    const int Kd = DD;       // 512

    float* Qw = (float*)d_ws;
    float* Kw = Qw + (size_t)M * N;
    float* Vw = Kw + (size_t)M * N;
    float* Ow = Vw + (size_t)M * N;

    dim3 gblk(N / 64, M / 64);
    gemm_deq<<<gblk, 256, 0, stream>>>(query, wq, bq, scale_q, zp_q, Qw, M, N, Kd);
    gemm_deq<<<gblk, 256, 0, stream>>>(key,   wk, bk, scale_k, zp_k, Kw, M, N, Kd);
    gemm_deq<<<gblk, 256, 0, stream>>>(value, wv, bv, scale_v, zp_v, Vw, M, N, Kd);

    dim3 gattn(LL / 64, HH, BB);
    attn_kernel<<<gattn, 256, 0, stream>>>(Qw, Kw, Vw, Ow);

    gemm_deq<<<gblk, 256, 0, stream>>>(Ow, wo, bo, scale_o, zp_o, (float*)d_out, M, N, Kd);
}

// Round 2
// 255.165 us; speedup vs baseline: 4.1741x; 4.1741x over previous
//
#include <hip/hip_runtime.h>
#include <math.h>
#include <stdint.h>

#define BB 4
#define LL 2048
#define DD 512
#define KDIM 64
#define HH 8

typedef _Float16 f16;
typedef f16 f16x8 __attribute__((ext_vector_type(8)));
typedef f16 f16x4v __attribute__((ext_vector_type(4)));
typedef float f32x4 __attribute__((ext_vector_type(4)));

// Involutive XOR swizzle: modifies byte bits 4-6 from bits 7-9. Works for both
// 64B-row (GEMM, BK=32 f16) and 128B-row (attn K, 64 f16) LDS tiles -> <=2-way.
__device__ __forceinline__ int swz(int x) { return x ^ (((x >> 7) & 7) << 4); }

__device__ __forceinline__ void gload16(const void* g, void* l) {
    __builtin_amdgcn_global_load_lds(
        (const __attribute__((address_space(1))) void*)g,
        (__attribute__((address_space(3))) void*)l, 16, 0, 0);
}

// ---------------------------------------------------------------------------
// Weight prep: W int32 [512 k][512 n] -> WT f16 [n][k], dequantized.
// ---------------------------------------------------------------------------
__global__ __launch_bounds__(256)
void prep_wt(const int* __restrict__ W, const float* __restrict__ scp,
             const float* __restrict__ zpp, f16* __restrict__ WT)
{
    __shared__ float t[32][33];
    const float sc = *scp, zp = *zpp;
    const int n0 = blockIdx.x * 32, k0 = blockIdx.y * 32;
    const int x = threadIdx.x & 31, y = threadIdx.x >> 5;  // 32 x 8
    #pragma unroll
    for (int i = 0; i < 32; i += 8)
        t[y + i][x] = ((float)W[(size_t)(k0 + y + i) * DD + n0 + x] - zp) * sc;
    __syncthreads();
    #pragma unroll
    for (int i = 0; i < 32; i += 8)
        WT[(size_t)(n0 + y + i) * DD + k0 + x] = (f16)t[x][y + i];
}

// ---------------------------------------------------------------------------
// fp32 -> fp16 cast (activations), 4 elems/thread.
// ---------------------------------------------------------------------------
__global__ __launch_bounds__(256)
void cast_f16(const float* __restrict__ in, f16* __restrict__ out)
{
    const int i = (blockIdx.x * 256 + threadIdx.x) * 4;
    float4 v = *(const float4*)(in + i);
    f16x4v o = {(f16)v.x, (f16)v.y, (f16)v.z, (f16)v.w};
    *(f16x4v*)(out + i) = o;
}

// ---------------------------------------------------------------------------
// MFMA GEMM: Out[M=8192][N=512] = A[M][512] @ WT^T + bias.
// 128x128 tile, BK=32, 4 waves (2x2), 4x4 16x16x32 frags per wave.
// EPI=0: scatter f16 to per-head [b*H+h][L][64] layout. EPI=1: fp32 [M][N].
// ---------------------------------------------------------------------------
template<int EPI>
__global__ __launch_bounds__(256)
void gemm_f16(const f16* __restrict__ A, const f16* __restrict__ BT,
              const float* __restrict__ bias, void* __restrict__ OutP)
{
    __shared__ __align__(16) char As[128 * 32 * 2];
    __shared__ __align__(16) char Bs[128 * 32 * 2];
    const int tid = threadIdx.x, lane = tid & 63, wid = tid >> 6;
    const int wm = wid >> 1, wn = wid & 1;
    const int rowBase = blockIdx.y * 128, colBase = blockIdx.x * 128;
    const f32x4 zero = {0.f, 0.f, 0.f, 0.f};
    f32x4 acc[4][4];
    #pragma unroll
    for (int i = 0; i < 4; ++i)
        #pragma unroll
        for (int j = 0; j < 4; ++j) acc[i][j] = zero;

    for (int kt = 0; kt < DD; kt += 32) {
        #pragma unroll
        for (int i = 0; i < 2; ++i) {
            const int xl = i * 4096 + wid * 1024 + lane * 16;
            const int xs = swz(xl);
            const int r = xs >> 6, cb = xs & 63;
            gload16((const char*)(A  + (size_t)(rowBase + r) * DD + kt) + cb, As + xl);
            gload16((const char*)(BT + (size_t)(colBase + r) * DD + kt) + cb, Bs + xl);
        }
        __syncthreads();
        f16x8 af[4], bf[4];
        #pragma unroll
        for (int mf = 0; mf < 4; ++mf)
            af[mf] = *(const f16x8*)(As + swz((wm * 64 + mf * 16 + (lane & 15)) * 64 + (lane >> 4) * 16));
        #pragma unroll
        for (int nf = 0; nf < 4; ++nf)
            bf[nf] = *(const f16x8*)(Bs + swz((wn * 64 + nf * 16 + (lane & 15)) * 64 + (lane >> 4) * 16));
        #pragma unroll
        for (int mf = 0; mf < 4; ++mf)
            #pragma unroll
            for (int nf = 0; nf < 4; ++nf)
                acc[mf][nf] = __builtin_amdgcn_mfma_f32_16x16x32_f16(af[mf], bf[nf], acc[mf][nf], 0, 0, 0);
        __syncthreads();
    }

    #pragma unroll
    for (int nf = 0; nf < 4; ++nf) {
        const int n = colBase + wn * 64 + nf * 16 + (lane & 15);
        const float bn = bias[n];
        #pragma unroll
        for (int mf = 0; mf < 4; ++mf) {
            #pragma unroll
            for (int r = 0; r < 4; ++r) {
                const int m = rowBase + wm * 64 + mf * 16 + (lane >> 4) * 4 + r;
                const float v = acc[mf][nf][r] + bn;
                if (EPI == 0) {
                    const int b = m >> 11, lr = m & 2047;
                    const int kd = n >> 3, h = n & 7;
                    ((f16*)OutP)[((size_t)(b * HH + h) * LL + lr) * KDIM + kd] = (f16)v;
                } else {
                    ((float*)OutP)[(size_t)m * DD + n] = v;
                }
            }
        }
    }
}

// ---------------------------------------------------------------------------
// MFMA flash attention. Grid (L/128, H, B); 4 waves x 32 q-rows each.
// Q/K/V fp16 in [b*H+h][L][64]; O scattered f16 to [b*L+q][kd*8+h].
// ---------------------------------------------------------------------------
__global__ __launch_bounds__(256)
void attn_f16(const f16* __restrict__ Qh, const f16* __restrict__ Kh,
              const f16* __restrict__ Vh, f16* __restrict__ Ob)
{
    __shared__ __align__(16) char k_s[64 * 64 * 2];   // swizzled [key][kd]
    __shared__ __align__(16) f16 vt_s[64][88];        // [kd][key], padded
    __shared__ __align__(16) f16 p_s[4][32][88];      // per-wave P

    const int tid = threadIdx.x, lane = tid & 63, wid = tid >> 6;
    const int qt = blockIdx.x, h = blockIdx.y, b = blockIdx.z;
    const int bh = b * HH + h;
    const f16* Qb = Qh + (size_t)bh * LL * KDIM;
    const f16* Kb = Kh + (size_t)bh * LL * KDIM;
    const f16* Vb = Vh + (size_t)bh * LL * KDIM;
    const int q0 = qt * 128 + wid * 32;

    // Q fragments in registers, pre-scaled by 1/sqrt(64) (exact in fp16)
    f16x8 qfr[2][2];
    #pragma unroll
    for (int i2 = 0; i2 < 2; ++i2)
        #pragma unroll
        for (int kb = 0; kb < 2; ++kb) {
            qfr[i2][kb] = *(const f16x8*)(Qb + (size_t)(q0 + i2 * 16 + (lane & 15)) * KDIM
                                          + kb * 32 + (lane >> 4) * 8);
            qfr[i2][kb] *= (f16)0.125f;
        }

    const f32x4 zero = {0.f, 0.f, 0.f, 0.f};
    f32x4 acc[2][4];
    float m_r[2][4], l_r[2][4];
    #pragma unroll
    for (int i2 = 0; i2 < 2; ++i2) {
        #pragma unroll
        for (int n = 0; n < 4; ++n) acc[i2][n] = zero;
        #pragma unroll
        for (int r = 0; r < 4; ++r) { m_r[i2][r] = -1e30f; l_r[i2][r] = 0.f; }
    }

    for (int kv = 0; kv < LL; kv += 64) {
        // stage K: contiguous 8KB, swizzled dest via pre-swizzled source
        #pragma unroll
        for (int i = 0; i < 2; ++i) {
            const int xl = i * 4096 + wid * 1024 + lane * 16;
            gload16((const char*)(Kb + (size_t)kv * KDIM) + swz(xl), k_s + xl);
        }
        // stage V transposed
        {
            const int key = tid >> 2, kd0 = (tid & 3) * 16;
            const f16* src = Vb + (size_t)(kv + key) * KDIM + kd0;
            f16x8 v0 = *(const f16x8*)src;
            f16x8 v1 = *(const f16x8*)(src + 8);
            #pragma unroll
            for (int j = 0; j < 8; ++j) vt_s[kd0 + j][key] = v0[j];
            #pragma unroll
            for (int j = 0; j < 8; ++j) vt_s[kd0 + 8 + j][key] = v1[j];
        }
        __syncthreads();

        // S = Q K^T
        f16x8 kfr[4][2];
        #pragma unroll
        for (int kf = 0; kf < 4; ++kf)
            #pragma unroll
            for (int kb = 0; kb < 2; ++kb)
                kfr[kf][kb] = *(const f16x8*)(k_s + swz((kf * 16 + (lane & 15)) * 128
                                                        + kb * 64 + (lane >> 4) * 16));
        f32x4 s[2][4];
        #pragma unroll
        for (int i2 = 0; i2 < 2; ++i2)
            #pragma unroll
            for (int kf = 0; kf < 4; ++kf) {
                f32x4 z = zero;
                z = __builtin_amdgcn_mfma_f32_16x16x32_f16(qfr[i2][0], kfr[kf][0], z, 0, 0, 0);
                z = __builtin_amdgcn_mfma_f32_16x16x32_f16(qfr[i2][1], kfr[kf][1], z, 0, 0, 0);
                s[i2][kf] = z;
            }

        // online softmax: rows live in 16-lane groups
        #pragma unroll
        for (int i2 = 0; i2 < 2; ++i2) {
            #pragma unroll
            for (int r = 0; r < 4; ++r) {
                float mx = fmaxf(fmaxf(s[i2][0][r], s[i2][1][r]),
                                 fmaxf(s[i2][2][r], s[i2][3][r]));
                mx = fmaxf(mx, __shfl_xor(mx, 1));
                mx = fmaxf(mx, __shfl_xor(mx, 2));
                mx = fmaxf(mx, __shfl_xor(mx, 4));
                mx = fmaxf(mx, __shfl_xor(mx, 8));
                const float mold = m_r[i2][r];
                const float mnew = fmaxf(mold, mx);
                const float f = __expf(mold - mnew);
                m_r[i2][r] = mnew;
                float ps = 0.f;
                #pragma unroll
                for (int kf = 0; kf < 4; ++kf) {
                    const float p = __expf(s[i2][kf][r] - mnew);
                    ps += p;
                    p_s[wid][i2 * 16 + (lane >> 4) * 4 + r][kf * 16 + (lane & 15)] = (f16)p;
                }
                ps += __shfl_xor(ps, 1);
                ps += __shfl_xor(ps, 2);
                ps += __shfl_xor(ps, 4);
                ps += __shfl_xor(ps, 8);
                l_r[i2][r] = l_r[i2][r] * f + ps;
                #pragma unroll
                for (int n = 0; n < 4; ++n) acc[i2][n][r] *= f;
            }
        }

        // O += P V
        #pragma unroll
        for (int kb = 0; kb < 2; ++kb) {
            f16x8 pf[2];
            #pragma unroll
            for (int i2 = 0; i2 < 2; ++i2)
                pf[i2] = *(const f16x8*)&p_s[wid][i2 * 16 + (lane & 15)][kb * 32 + (lane >> 4) * 8];
            #pragma unroll
            for (int n = 0; n < 4; ++n) {
                f16x8 vf = *(const f16x8*)&vt_s[n * 16 + (lane & 15)][kb * 32 + (lane >> 4) * 8];
                #pragma unroll
                for (int i2 = 0; i2 < 2; ++i2)
                    acc[i2][n] = __builtin_amdgcn_mfma_f32_16x16x32_f16(pf[i2], vf, acc[i2][n], 0, 0, 0);
            }
        }
        __syncthreads();
    }

    // epilogue: normalize, scatter to [b*L+q][kd*8+h] f16
    #pragma unroll
    for (int i2 = 0; i2 < 2; ++i2)
        #pragma unroll
        for (int r = 0; r < 4; ++r) {
            const float inv = 1.f / l_r[i2][r];
            const int q = q0 + i2 * 16 + (lane >> 4) * 4 + r;
            #pragma unroll
            for (int n = 0; n < 4; ++n) {
                const int kd = n * 16 + (lane & 15);
                Ob[(size_t)(b * LL + q) * DD + kd * HH + h] = (f16)(acc[i2][n][r] * inv);
            }
        }
}

// ---------------------------------------------------------------------------
extern "C" void kernel_launch(void* const* d_in, const int* in_sizes, int n_in,
                              void* d_out, int out_size, void* d_ws, size_t ws_size,
                              hipStream_t stream)
{
    const float* query = (const float*)d_in[0];
    const float* key   = (const float*)d_in[1];
    const float* value = (const float*)d_in[2];
    const int* wq = (const int*)d_in[3];
    const int* wk = (const int*)d_in[4];
    const int* wv = (const int*)d_in[5];
    const int* wo = (const int*)d_in[6];
    const float* bq = (const float*)d_in[7];
    const float* bk = (const float*)d_in[8];
    const float* bv = (const float*)d_in[9];
    const float* bo = (const float*)d_in[10];
    const float* scale_q = (const float*)d_in[11];
    const float* scale_k = (const float*)d_in[12];
    const float* scale_v = (const float*)d_in[13];
    const float* scale_o = (const float*)d_in[14];
    const float* zp_q = (const float*)d_in[15];
    const float* zp_k = (const float*)d_in[16];
    const float* zp_v = (const float*)d_in[17];
    const float* zp_o = (const float*)d_in[18];

    const size_t MD = (size_t)BB * LL * DD;       // 4.19M
    const size_t WT_SZ = (size_t)DD * DD;         // 262K

    f16* Xq  = (f16*)d_ws;
    f16* Xk  = Xq + MD;
    f16* Xv  = Xk + MD;
    f16* WTq = Xv + MD;
    f16* WTk = WTq + WT_SZ;
    f16* WTv = WTk + WT_SZ;
    f16* WTo = WTv + WT_SZ;
    f16* Qh  = WTo + WT_SZ;
    f16* Kh  = Qh + MD;
    f16* Vh  = Kh + MD;
    f16* Ob  = Vh + MD;

    dim3 gprep(16, 16);
    prep_wt<<<gprep, 256, 0, stream>>>(wq, scale_q, zp_q, WTq);
    prep_wt<<<gprep, 256, 0, stream>>>(wk, scale_k, zp_k, WTk);
    prep_wt<<<gprep, 256, 0, stream>>>(wv, scale_v, zp_v, WTv);
    prep_wt<<<gprep, 256, 0, stream>>>(wo, scale_o, zp_o, WTo);

    const int castBlocks = (int)(MD / 4 / 256);   // 4096
    cast_f16<<<castBlocks, 256, 0, stream>>>(query, Xq);
    cast_f16<<<castBlocks, 256, 0, stream>>>(key,   Xk);
    cast_f16<<<castBlocks, 256, 0, stream>>>(value, Xv);

    dim3 ggemm(DD / 128, BB * LL / 128);          // (4, 64)
    gemm_f16<0><<<ggemm, 256, 0, stream>>>(Xq, WTq, bq, Qh);
    gemm_f16<0><<<ggemm, 256, 0, stream>>>(Xk, WTk, bk, Kh);
    gemm_f16<0><<<ggemm, 256, 0, stream>>>(Xv, WTv, bv, Vh);

    dim3 gattn(LL / 128, HH, BB);                 // (16, 8, 4)
    attn_f16<<<gattn, 256, 0, stream>>>(Qh, Kh, Vh, Ob);

    gemm_f16<1><<<ggemm, 256, 0, stream>>>(Ob, WTo, bo, d_out);
}

// Round 3
// 201.775 us; speedup vs baseline: 5.2786x; 1.2646x over previous
//
#include <hip/hip_runtime.h>
#include <math.h>
#include <stdint.h>

#define BB 4
#define LL 2048
#define DD 512
#define KDIM 64
#define HH 8

typedef _Float16 f16;
typedef f16 f16x8 __attribute__((ext_vector_type(8)));
typedef f16 f16x4v __attribute__((ext_vector_type(4)));
typedef float f32x4 __attribute__((ext_vector_type(4)));

// Involutive XOR swizzle for 128B-row LDS tiles (and 64B GEMM rows).
__device__ __forceinline__ int swz(int x) { return x ^ (((x >> 7) & 7) << 4); }

__device__ __forceinline__ void gload16(const void* g, void* l) {
    __builtin_amdgcn_global_load_lds(
        (const __attribute__((address_space(1))) void*)g,
        (__attribute__((address_space(3))) void*)l, 16, 0, 0);
}

// ---------------------------------------------------------------------------
// Weight prep: W int32 [512 k][512 n] -> WT f16 [n][k], dequantized.
// ---------------------------------------------------------------------------
__global__ __launch_bounds__(256)
void prep_wt(const int* __restrict__ W, const float* __restrict__ scp,
             const float* __restrict__ zpp, f16* __restrict__ WT)
{
    __shared__ float t[32][33];
    const float sc = *scp, zp = *zpp;
    const int n0 = blockIdx.x * 32, k0 = blockIdx.y * 32;
    const int x = threadIdx.x & 31, y = threadIdx.x >> 5;  // 32 x 8
    #pragma unroll
    for (int i = 0; i < 32; i += 8)
        t[y + i][x] = ((float)W[(size_t)(k0 + y + i) * DD + n0 + x] - zp) * sc;
    __syncthreads();
    #pragma unroll
    for (int i = 0; i < 32; i += 8)
        WT[(size_t)(n0 + y + i) * DD + k0 + x] = (f16)t[x][y + i];
}

// ---------------------------------------------------------------------------
// fp32 -> fp16 cast (activations), 4 elems/thread.
// ---------------------------------------------------------------------------
__global__ __launch_bounds__(256)
void cast_f16(const float* __restrict__ in, f16* __restrict__ out)
{
    const int i = (blockIdx.x * 256 + threadIdx.x) * 4;
    float4 v = *(const float4*)(in + i);
    f16x4v o = {(f16)v.x, (f16)v.y, (f16)v.z, (f16)v.w};
    *(f16x4v*)(out + i) = o;
}

// ---------------------------------------------------------------------------
// MFMA GEMM: Out[M=8192][N=512] = A[M][512] @ WT^T + bias.
// 128x128 tile, BK=32, 4 waves (2x2), 4x4 16x16x32 frags per wave.
// EPI=0: f16 per-head row-major [b*H+h][L][64]     (Q, K)
// EPI=1: fp32 [M][N]                               (final output)
// EPI=2: f16 per-head col-major [b*H+h][64][L]     (V, pre-transposed)
// ---------------------------------------------------------------------------
template<int EPI>
__global__ __launch_bounds__(256)
void gemm_f16(const f16* __restrict__ A, const f16* __restrict__ BT,
              const float* __restrict__ bias, void* __restrict__ OutP)
{
    __shared__ __align__(16) char As[128 * 32 * 2];
    __shared__ __align__(16) char Bs[128 * 32 * 2];
    const int tid = threadIdx.x, lane = tid & 63, wid = tid >> 6;
    const int g = lane >> 4, ql = lane & 15;
    const int wm = wid >> 1, wn = wid & 1;
    // XCD swizzle: 32 consecutive tiles per XCD (A-panel locality)
    const int bid = blockIdx.x;
    const int sb = (bid & 7) * 32 + (bid >> 3);
    const int rowBase = (sb >> 2) * 128, colBase = (sb & 3) * 128;

    const f32x4 zero = {0.f, 0.f, 0.f, 0.f};
    f32x4 acc[4][4];
    #pragma unroll
    for (int i = 0; i < 4; ++i)
        #pragma unroll
        for (int j = 0; j < 4; ++j) acc[i][j] = zero;

    for (int kt = 0; kt < DD; kt += 32) {
        #pragma unroll
        for (int i = 0; i < 2; ++i) {
            const int xl = i * 4096 + wid * 1024 + lane * 16;
            const int xs = swz(xl);
            const int r = xs >> 6, cb = xs & 63;
            gload16((const char*)(A  + (size_t)(rowBase + r) * DD + kt) + cb, As + xl);
            gload16((const char*)(BT + (size_t)(colBase + r) * DD + kt) + cb, Bs + xl);
        }
        __syncthreads();
        f16x8 af[4], bf[4];
        #pragma unroll
        for (int mf = 0; mf < 4; ++mf)
            af[mf] = *(const f16x8*)(As + swz((wm * 64 + mf * 16 + ql) * 64 + g * 16));
        #pragma unroll
        for (int nf = 0; nf < 4; ++nf)
            bf[nf] = *(const f16x8*)(Bs + swz((wn * 64 + nf * 16 + ql) * 64 + g * 16));
        #pragma unroll
        for (int mf = 0; mf < 4; ++mf)
            #pragma unroll
            for (int nf = 0; nf < 4; ++nf)
                acc[mf][nf] = __builtin_amdgcn_mfma_f32_16x16x32_f16(af[mf], bf[nf], acc[mf][nf], 0, 0, 0);
        __syncthreads();
    }

    #pragma unroll
    for (int nf = 0; nf < 4; ++nf) {
        const int n = colBase + wn * 64 + nf * 16 + ql;
        const float bn = bias[n];
        #pragma unroll
        for (int mf = 0; mf < 4; ++mf) {
            const int m0 = rowBase + wm * 64 + mf * 16 + g * 4;
            if (EPI == 2) {
                // V: col-major per head, 4 consecutive l -> one 8B store
                const int b = m0 >> 11, l0 = m0 & 2047;
                const int kd = n >> 3, hh = n & 7;
                f16x4v o = {(f16)(acc[mf][nf][0] + bn), (f16)(acc[mf][nf][1] + bn),
                            (f16)(acc[mf][nf][2] + bn), (f16)(acc[mf][nf][3] + bn)};
                *(f16x4v*)((f16*)OutP + ((size_t)(b * HH + hh) * KDIM + kd) * LL + l0) = o;
            } else {
                #pragma unroll
                for (int r = 0; r < 4; ++r) {
                    const int m = m0 + r;
                    const float v = acc[mf][nf][r] + bn;
                    if (EPI == 0) {
                        const int b = m >> 11, lr = m & 2047;
                        const int kd = n >> 3, hh = n & 7;
                        ((f16*)OutP)[((size_t)(b * HH + hh) * LL + lr) * KDIM + kd] = (f16)v;
                    } else {
                        ((float*)OutP)[(size_t)m * DD + n] = v;
                    }
                }
            }
        }
    }
}

// ---------------------------------------------------------------------------
// MFMA flash attention, fully transposed dataflow (S^T and O^T) so the
// softmax reduction axis is register-local per lane (q = lane&15).
// Q,K in [b*H+h][L][64]; V in [b*H+h][64][L]; O scattered to [b*L+q][kd*8+h].
// ---------------------------------------------------------------------------
__global__ __launch_bounds__(256, 4)
void attn_f16(const f16* __restrict__ Qh, const f16* __restrict__ Kh,
              const f16* __restrict__ VhT, f16* __restrict__ Ob)
{
    __shared__ __align__(16) char k_s[64 * 128];   // [key][kd] swizzled, 8KB
    __shared__ __align__(16) char v_s[64 * 128];   // [kd][key] swizzled, 8KB
    __shared__ __align__(16) f16 p_s[4][32][72];   // per-wave P^T as [q][key]

    const int tid = threadIdx.x, lane = tid & 63, wid = tid >> 6;
    const int g = lane >> 4, ql = lane & 15;

    // XCD swizzle: 64 consecutive sub-blocks (4 bh-groups) per XCD -> K/V L2-resident
    const int bid = blockIdx.x;                    // 0..511
    const int sb = (bid & 7) * 64 + (bid >> 3);
    const int qt = sb & 15, bh = sb >> 4;
    const int h = bh & 7, b = bh >> 3;

    const f16*  Qb = Qh + (size_t)bh * LL * KDIM;
    const char* Kb = (const char*)(Kh + (size_t)bh * LL * KDIM);
    const char* Vb = (const char*)(VhT + (size_t)bh * KDIM * LL);
    const int q0 = qt * 128 + wid * 32;

    // Q fragments (B-operand: col=q, k=kd), pre-scaled by 1/8 * log2(e)
    const f16 qscale = (f16)(0.125f * 1.44269504089f);
    f16x8 qfr[2][2];
    #pragma unroll
    for (int i2 = 0; i2 < 2; ++i2)
        #pragma unroll
        for (int kb = 0; kb < 2; ++kb) {
            qfr[i2][kb] = *(const f16x8*)(Qb + (size_t)(q0 + i2 * 16 + ql) * KDIM
                                          + kb * 32 + g * 8);
            qfr[i2][kb] *= qscale;
        }

    const f32x4 zero = {0.f, 0.f, 0.f, 0.f};
    f32x4 acc[2][4];
    float m_r[2], l_r[2];
    #pragma unroll
    for (int i2 = 0; i2 < 2; ++i2) {
        m_r[i2] = -1e30f; l_r[i2] = 0.f;
        #pragma unroll
        for (int n = 0; n < 4; ++n) acc[i2][n] = zero;
    }

    for (int kv = 0; kv < LL; kv += 64) {
        // stage K tile (contiguous slab) and V^T tile (64 rows, stride L)
        #pragma unroll
        for (int i = 0; i < 2; ++i) {
            const int xl = i * 4096 + wid * 1024 + lane * 16;
            const int xs = swz(xl);
            gload16(Kb + (size_t)kv * 128 + xs, k_s + xl);
            gload16(Vb + (size_t)(xs >> 7) * (LL * 2) + (size_t)kv * 2 + (xs & 127),
                    v_s + xl);
        }
        __syncthreads();

        // K fragments (A-operand: row=key, k=kd)
        f16x8 kfr[4][2];
        #pragma unroll
        for (int kf = 0; kf < 4; ++kf)
            #pragma unroll
            for (int kb = 0; kb < 2; ++kb)
                kfr[kf][kb] = *(const f16x8*)(k_s + swz((kf * 16 + ql) * 128
                                                        + kb * 64 + g * 16));

        #pragma unroll
        for (int i2 = 0; i2 < 2; ++i2) {
            // S^T = K Q^T : col = q (lane-local), rows = keys
            f32x4 s[4];
            #pragma unroll
            for (int kf = 0; kf < 4; ++kf) {
                f32x4 z = zero;
                z = __builtin_amdgcn_mfma_f32_16x16x32_f16(kfr[kf][0], qfr[i2][0], z, 0, 0, 0);
                z = __builtin_amdgcn_mfma_f32_16x16x32_f16(kfr[kf][1], qfr[i2][1], z, 0, 0, 0);
                s[kf] = z;
            }
            // online softmax: 16 scores in-register, 2 shfls to cover 64 keys
            float mx = s[0][0];
            #pragma unroll
            for (int kf = 0; kf < 4; ++kf)
                #pragma unroll
                for (int r = 0; r < 4; ++r) mx = fmaxf(mx, s[kf][r]);
            mx = fmaxf(mx, __shfl_xor(mx, 16));
            mx = fmaxf(mx, __shfl_xor(mx, 32));
            const float mnew = fmaxf(m_r[i2], mx);
            const float fsc = exp2f(m_r[i2] - mnew);
            m_r[i2] = mnew;
            float ps = 0.f;
            #pragma unroll
            for (int kf = 0; kf < 4; ++kf) {
                const float p0 = exp2f(s[kf][0] - mnew);
                const float p1 = exp2f(s[kf][1] - mnew);
                const float p2 = exp2f(s[kf][2] - mnew);
                const float p3 = exp2f(s[kf][3] - mnew);
                ps += (p0 + p1) + (p2 + p3);
                f16x4v pk = {(f16)p0, (f16)p1, (f16)p2, (f16)p3};
                *(f16x4v*)&p_s[wid][i2 * 16 + ql][kf * 16 + g * 4] = pk;
            }
            ps += __shfl_xor(ps, 16);
            ps += __shfl_xor(ps, 32);
            l_r[i2] = l_r[i2] * fsc + ps;
            #pragma unroll
            for (int n = 0; n < 4; ++n) acc[i2][n] *= fsc;
        }

        // O^T += V^T P^T  (A = V^T frag: row=d; B = P^T frag: col=q)
        #pragma unroll
        for (int kb = 0; kb < 2; ++kb) {
            f16x8 pf[2];
            #pragma unroll
            for (int i2 = 0; i2 < 2; ++i2)
                pf[i2] = *(const f16x8*)&p_s[wid][i2 * 16 + ql][kb * 32 + g * 8];
            #pragma unroll
            for (int n = 0; n < 4; ++n) {
                f16x8 vf = *(const f16x8*)(v_s + swz((n * 16 + ql) * 128
                                                     + kb * 64 + g * 16));
                #pragma unroll
                for (int i2 = 0; i2 < 2; ++i2)
                    acc[i2][n] = __builtin_amdgcn_mfma_f32_16x16x32_f16(vf, pf[i2], acc[i2][n], 0, 0, 0);
            }
        }
        __syncthreads();
    }

    // epilogue: normalize (per-lane, no shfl), scatter to [b*L+q][kd*8+h]
    #pragma unroll
    for (int i2 = 0; i2 < 2; ++i2) {
        const float inv = 1.f / l_r[i2];
        const int q = q0 + i2 * 16 + ql;
        f16* orow = Ob + (size_t)(b * LL + q) * DD + h;
        #pragma unroll
        for (int n = 0; n < 4; ++n)
            #pragma unroll
            for (int r = 0; r < 4; ++r) {
                const int d = n * 16 + g * 4 + r;
                orow[d * HH] = (f16)(acc[i2][n][r] * inv);
            }
    }
}

// ---------------------------------------------------------------------------
extern "C" void kernel_launch(void* const* d_in, const int* in_sizes, int n_in,
                              void* d_out, int out_size, void* d_ws, size_t ws_size,
                              hipStream_t stream)
{
    const float* query = (const float*)d_in[0];
    const float* key   = (const float*)d_in[1];
    const float* value = (const float*)d_in[2];
    const int* wq = (const int*)d_in[3];
    const int* wk = (const int*)d_in[4];
    const int* wv = (const int*)d_in[5];
    const int* wo = (const int*)d_in[6];
    const float* bq = (const float*)d_in[7];
    const float* bk = (const float*)d_in[8];
    const float* bv = (const float*)d_in[9];
    const float* bo = (const float*)d_in[10];
    const float* scale_q = (const float*)d_in[11];
    const float* scale_k = (const float*)d_in[12];
    const float* scale_v = (const float*)d_in[13];
    const float* scale_o = (const float*)d_in[14];
    const float* zp_q = (const float*)d_in[15];
    const float* zp_k = (const float*)d_in[16];
    const float* zp_v = (const float*)d_in[17];
    const float* zp_o = (const float*)d_in[18];

    const size_t MD = (size_t)BB * LL * DD;       // 4.19M
    const size_t WT_SZ = (size_t)DD * DD;

    f16* Xq  = (f16*)d_ws;
    f16* Xk  = Xq + MD;
    f16* Xv  = Xk + MD;
    f16* WTq = Xv + MD;
    f16* WTk = WTq + WT_SZ;
    f16* WTv = WTk + WT_SZ;
    f16* WTo = WTv + WT_SZ;
    f16* Qh  = WTo + WT_SZ;
    f16* Kh  = Qh + MD;
    f16* VhT = Kh + MD;
    f16* Ob  = VhT + MD;

    dim3 gprep(16, 16);
    prep_wt<<<gprep, 256, 0, stream>>>(wq, scale_q, zp_q, WTq);
    prep_wt<<<gprep, 256, 0, stream>>>(wk, scale_k, zp_k, WTk);
    prep_wt<<<gprep, 256, 0, stream>>>(wv, scale_v, zp_v, WTv);
    prep_wt<<<gprep, 256, 0, stream>>>(wo, scale_o, zp_o, WTo);

    const int castBlocks = (int)(MD / 4 / 256);   // 4096
    cast_f16<<<castBlocks, 256, 0, stream>>>(query, Xq);
    cast_f16<<<castBlocks, 256, 0, stream>>>(key,   Xk);
    cast_f16<<<castBlocks, 256, 0, stream>>>(value, Xv);

    gemm_f16<0><<<256, 256, 0, stream>>>(Xq, WTq, bq, Qh);
    gemm_f16<0><<<256, 256, 0, stream>>>(Xk, WTk, bk, Kh);
    gemm_f16<2><<<256, 256, 0, stream>>>(Xv, WTv, bv, VhT);

    attn_f16<<<512, 256, 0, stream>>>(Qh, Kh, VhT, Ob);

    gemm_f16<1><<<256, 256, 0, stream>>>(Ob, WTo, bo, d_out);
}

// Round 4
// 151.850 us; speedup vs baseline: 7.0141x; 1.3288x over previous
//
#include <hip/hip_runtime.h>
#include <math.h>
#include <stdint.h>

#define BB 4
#define LL 2048
#define DD 512
#define KDIM 64
#define HH 8

typedef _Float16 f16;
typedef f16 f16x8 __attribute__((ext_vector_type(8)));
typedef f16 f16x4v __attribute__((ext_vector_type(4)));
typedef float f32x4 __attribute__((ext_vector_type(4)));

// Involutive XOR swizzle for 128B-row (attn) and 64B-row (GEMM) LDS tiles.
__device__ __forceinline__ int swz(int x) { return x ^ (((x >> 7) & 7) << 4); }

__device__ __forceinline__ void gload16(const void* g, void* l) {
    __builtin_amdgcn_global_load_lds(
        (const __attribute__((address_space(1))) void*)g,
        (__attribute__((address_space(3))) void*)l, 16, 0, 0);
}

// ---------------------------------------------------------------------------
// Weight prep (all 4 in one launch, blockIdx.z selects).
// W int32 [512 k][512 n] -> WT f16 [n][k], dequantized.
// z==3 (WO): k-index permuted k' = (k&7)*64 + (k>>3) so the final GEMM can
// read the attention output in per-head [b][h][q][64] layout.
// ---------------------------------------------------------------------------
__global__ __launch_bounds__(256)
void prep_all(const int* __restrict__ w0, const int* __restrict__ w1,
              const int* __restrict__ w2, const int* __restrict__ w3,
              const float* s0, const float* s1, const float* s2, const float* s3,
              const float* z0, const float* z1, const float* z2, const float* z3,
              f16* o0, f16* o1, f16* o2, f16* o3)
{
    __shared__ float t[32][33];
    const int zi = blockIdx.z;
    const int* W = zi == 0 ? w0 : zi == 1 ? w1 : zi == 2 ? w2 : w3;
    const float sc = *(zi == 0 ? s0 : zi == 1 ? s1 : zi == 2 ? s2 : s3);
    const float zp = *(zi == 0 ? z0 : zi == 1 ? z1 : zi == 2 ? z2 : z3);
    f16* WT = zi == 0 ? o0 : zi == 1 ? o1 : zi == 2 ? o2 : o3;
    const int n0 = blockIdx.x * 32, k0 = blockIdx.y * 32;
    const int x = threadIdx.x & 31, y = threadIdx.x >> 5;  // 32 x 8
    #pragma unroll
    for (int i = 0; i < 32; i += 8)
        t[y + i][x] = ((float)W[(size_t)(k0 + y + i) * DD + n0 + x] - zp) * sc;
    __syncthreads();
    if (zi == 3) {
        const int k = k0 + x;
        const int kp = (k & 7) * 64 + (k >> 3);
        #pragma unroll
        for (int i = 0; i < 32; i += 8)
            WT[(size_t)(n0 + y + i) * DD + kp] = (f16)t[x][y + i];
    } else {
        #pragma unroll
        for (int i = 0; i < 32; i += 8)
            WT[(size_t)(n0 + y + i) * DD + k0 + x] = (f16)t[x][y + i];
    }
}

// ---------------------------------------------------------------------------
// fp32 -> fp16 cast, all 3 activations in one launch (blockIdx.y selects).
// ---------------------------------------------------------------------------
__global__ __launch_bounds__(256)
void cast_all(const float* __restrict__ q, const float* __restrict__ k,
              const float* __restrict__ v, f16* oq, f16* ok, f16* ov)
{
    const int yi = blockIdx.y;
    const float* in = yi == 0 ? q : yi == 1 ? k : v;
    f16* out = yi == 0 ? oq : yi == 1 ? ok : ov;
    const int i = (blockIdx.x * 256 + threadIdx.x) * 4;
    float4 x = *(const float4*)(in + i);
    f16x4v o = {(f16)x.x, (f16)x.y, (f16)x.z, (f16)x.w};
    *(f16x4v*)(out + i) = o;
}

// ---------------------------------------------------------------------------
// MFMA GEMM body: Out[M=8192][N=512] = A[M][512] @ WT^T + bias.
// 128x128 tile, BK=32, 4 waves (2x2), 4x4 16x16x32 frags per wave.
// EPI=0: f16 per-head row-major [b*H+h][L][64]     (Q, K)
// EPI=1: fp32 [M][N]; A is per-head [b][h][q][64] with permuted-k weights
// EPI=2: f16 per-head col-major [b*H+h][64][L]     (V, pre-transposed)
// ---------------------------------------------------------------------------
template<int EPI>
__device__ __forceinline__
void gemm_body(char* As, char* Bs, const f16* __restrict__ A,
               const f16* __restrict__ BT, const float* __restrict__ bias,
               void* __restrict__ OutP)
{
    const int tid = threadIdx.x, lane = tid & 63, wid = tid >> 6;
    const int g = lane >> 4, ql = lane & 15;
    const int wm = wid >> 1, wn = wid & 1;
    const int bid = blockIdx.x;
    const int sb = (bid & 7) * 32 + (bid >> 3);    // XCD swizzle (256 blocks)
    const int rowBase = (sb >> 2) * 128, colBase = (sb & 3) * 128;

    const f32x4 zero = {0.f, 0.f, 0.f, 0.f};
    f32x4 acc[4][4];
    #pragma unroll
    for (int i = 0; i < 4; ++i)
        #pragma unroll
        for (int j = 0; j < 4; ++j) acc[i][j] = zero;

    for (int kt = 0; kt < DD; kt += 32) {
        #pragma unroll
        for (int i = 0; i < 2; ++i) {
            const int xl = i * 4096 + wid * 1024 + lane * 16;
            const int xs = swz(xl);
            const int r = xs >> 6, cb = xs & 63;
            const char* asrc;
            if (EPI == 1) {
                // A row m, k-bytes kp: head-interleaved gather
                const int m = rowBase + r, b = m >> 11, qq = m & 2047;
                const int kp = kt * 2 + cb;
                asrc = (const char*)A +
                       (((size_t)((b * 8 + (kp >> 7)) * 2048 + qq)) << 7) + (kp & 127);
            } else {
                asrc = (const char*)(A + (size_t)(rowBase + r) * DD + kt) + cb;
            }
            gload16(asrc, As + xl);
            gload16((const char*)(BT + (size_t)(colBase + r) * DD + kt) + cb, Bs + xl);
        }
        __syncthreads();
        f16x8 af[4], bf[4];
        #pragma unroll
        for (int mf = 0; mf < 4; ++mf)
            af[mf] = *(const f16x8*)(As + swz((wm * 64 + mf * 16 + ql) * 64 + g * 16));
        #pragma unroll
        for (int nf = 0; nf < 4; ++nf)
            bf[nf] = *(const f16x8*)(Bs + swz((wn * 64 + nf * 16 + ql) * 64 + g * 16));
        __builtin_amdgcn_s_setprio(1);
        #pragma unroll
        for (int mf = 0; mf < 4; ++mf)
            #pragma unroll
            for (int nf = 0; nf < 4; ++nf)
                acc[mf][nf] = __builtin_amdgcn_mfma_f32_16x16x32_f16(af[mf], bf[nf], acc[mf][nf], 0, 0, 0);
        __builtin_amdgcn_s_setprio(0);
        __syncthreads();
    }

    #pragma unroll
    for (int nf = 0; nf < 4; ++nf) {
        const int n = colBase + wn * 64 + nf * 16 + ql;
        const float bn = bias[n];
        #pragma unroll
        for (int mf = 0; mf < 4; ++mf) {
            const int m0 = rowBase + wm * 64 + mf * 16 + g * 4;
            if (EPI == 2) {
                const int b = m0 >> 11, l0 = m0 & 2047;
                const int kd = n >> 3, hh = n & 7;
                f16x4v o = {(f16)(acc[mf][nf][0] + bn), (f16)(acc[mf][nf][1] + bn),
                            (f16)(acc[mf][nf][2] + bn), (f16)(acc[mf][nf][3] + bn)};
                *(f16x4v*)((f16*)OutP + ((size_t)(b * HH + hh) * KDIM + kd) * LL + l0) = o;
            } else {
                #pragma unroll
                for (int r = 0; r < 4; ++r) {
                    const int m = m0 + r;
                    const float v = acc[mf][nf][r] + bn;
                    if (EPI == 0) {
                        const int b = m >> 11, lr = m & 2047;
                        const int kd = n >> 3, hh = n & 7;
                        ((f16*)OutP)[((size_t)(b * HH + hh) * LL + lr) * KDIM + kd] = (f16)v;
                    } else {
                        ((float*)OutP)[(size_t)m * DD + n] = v;
                    }
                }
            }
        }
    }
}

__global__ __launch_bounds__(256)
void gemm_qkv(const f16* Xq, const f16* Xk, const f16* Xv,
              const f16* WTq, const f16* WTk, const f16* WTv,
              const float* bq, const float* bk, const float* bv,
              f16* Qh, f16* Kh, f16* VhT)
{
    __shared__ __align__(16) char As[128 * 32 * 2];
    __shared__ __align__(16) char Bs[128 * 32 * 2];
    const int z = blockIdx.z;
    if (z == 0)      gemm_body<0>(As, Bs, Xq, WTq, bq, Qh);
    else if (z == 1) gemm_body<0>(As, Bs, Xk, WTk, bk, Kh);
    else             gemm_body<2>(As, Bs, Xv, WTv, bv, VhT);
}

__global__ __launch_bounds__(256)
void gemm_out(const f16* A, const f16* BT, const float* bias, float* Out)
{
    __shared__ __align__(16) char As[128 * 32 * 2];
    __shared__ __align__(16) char Bs[128 * 32 * 2];
    gemm_body<1>(As, Bs, A, BT, bias, Out);
}

// ---------------------------------------------------------------------------
// MFMA flash attention, transposed dataflow (S^T / O^T), QB=64 per block,
// 4 waves x 16 q-rows. Grid 1024 -> 4 blocks/CU. Defer-max softmax.
// Q,K in [bh][L][64]; V in [bh][64][L]; O in [bh][L][64] (packed 8B stores).
// ---------------------------------------------------------------------------
__global__ __launch_bounds__(256, 4)
void attn_f16(const f16* __restrict__ Qh, const f16* __restrict__ Kh,
              const f16* __restrict__ VhT, f16* __restrict__ Ob)
{
    __shared__ __align__(16) char k_s[64 * 128];   // [key][kd] swizzled, 8KB
    __shared__ __align__(16) char v_s[64 * 128];   // [kd][key] swizzled, 8KB
    __shared__ __align__(16) f16 p_s[4][16][72];   // per-wave P^T as [q][key]

    const int tid = threadIdx.x, lane = tid & 63, wid = tid >> 6;
    const int g = lane >> 4, ql = lane & 15;

    // XCD swizzle: 128 consecutive sb (4 bh) per XCD -> K/V L2-resident
    const int bid = blockIdx.x;                    // 0..1023
    const int sb = (bid & 7) * 128 + (bid >> 3);
    const int qt = sb & 31, bh = sb >> 5;

    const f16*  Qb = Qh + (size_t)bh * LL * KDIM;
    const char* Kb = (const char*)(Kh + (size_t)bh * LL * KDIM);
    const char* Vb = (const char*)(VhT + (size_t)bh * KDIM * LL);
    const int q0 = qt * 64 + wid * 16;

    // Q fragment (B-operand: col=q, k=kd), scaled by 1/8 * log2(e)
    const f16 qscale = (f16)(0.125f * 1.44269504089f);
    f16x8 qfr[2];
    #pragma unroll
    for (int kb = 0; kb < 2; ++kb) {
        qfr[kb] = *(const f16x8*)(Qb + (size_t)(q0 + ql) * KDIM + kb * 32 + g * 8);
        qfr[kb] *= qscale;
    }

    const f32x4 zero = {0.f, 0.f, 0.f, 0.f};
    f32x4 acc[4];
    #pragma unroll
    for (int n = 0; n < 4; ++n) acc[n] = zero;
    float m_r = -1e30f, l_r = 0.f;

    for (int kv = 0; kv < LL; kv += 64) {
        #pragma unroll
        for (int i = 0; i < 2; ++i) {
            const int xl = i * 4096 + wid * 1024 + lane * 16;
            const int xs = swz(xl);
            gload16(Kb + (size_t)kv * 128 + xs, k_s + xl);
            gload16(Vb + (size_t)(xs >> 7) * (LL * 2) + (size_t)kv * 2 + (xs & 127),
                    v_s + xl);
        }
        __syncthreads();

        // S^T = K Q^T : col = q (lane-local), rows = 64 keys
        f32x4 s[4];
        __builtin_amdgcn_s_setprio(1);
        #pragma unroll
        for (int kf = 0; kf < 4; ++kf) {
            f16x8 kfr0 = *(const f16x8*)(k_s + swz((kf * 16 + ql) * 128 + g * 16));
            f16x8 kfr1 = *(const f16x8*)(k_s + swz((kf * 16 + ql) * 128 + 64 + g * 16));
            f32x4 z = zero;
            z = __builtin_amdgcn_mfma_f32_16x16x32_f16(kfr0, qfr[0], z, 0, 0, 0);
            z = __builtin_amdgcn_mfma_f32_16x16x32_f16(kfr1, qfr[1], z, 0, 0, 0);
            s[kf] = z;
        }
        __builtin_amdgcn_s_setprio(0);

        // online softmax with defer-max (THR=8 in exp2 domain)
        float mx = s[0][0];
        #pragma unroll
        for (int kf = 0; kf < 4; ++kf)
            #pragma unroll
            for (int r = 0; r < 4; ++r) mx = fmaxf(mx, s[kf][r]);
        mx = fmaxf(mx, __shfl_xor(mx, 16));
        mx = fmaxf(mx, __shfl_xor(mx, 32));
        if (__any(mx > m_r + 8.f)) {
            const float mnew = fmaxf(m_r, mx);
            const float fsc = exp2f(m_r - mnew);
            m_r = mnew;
            l_r *= fsc;
            #pragma unroll
            for (int n = 0; n < 4; ++n) acc[n] *= fsc;
        }
        float ps = 0.f;
        #pragma unroll
        for (int kf = 0; kf < 4; ++kf) {
            const float p0 = exp2f(s[kf][0] - m_r);
            const float p1 = exp2f(s[kf][1] - m_r);
            const float p2 = exp2f(s[kf][2] - m_r);
            const float p3 = exp2f(s[kf][3] - m_r);
            ps += (p0 + p1) + (p2 + p3);
            f16x4v pk = {(f16)p0, (f16)p1, (f16)p2, (f16)p3};
            *(f16x4v*)&p_s[wid][ql][kf * 16 + g * 4] = pk;
        }
        l_r += ps;   // per-lane partial; cross-lane reduced once at epilogue

        // O^T += V^T P^T
        __builtin_amdgcn_s_setprio(1);
        #pragma unroll
        for (int kb = 0; kb < 2; ++kb) {
            f16x8 pf = *(const f16x8*)&p_s[wid][ql][kb * 32 + g * 8];
            #pragma unroll
            for (int n = 0; n < 4; ++n) {
                f16x8 vf = *(const f16x8*)(v_s + swz((n * 16 + ql) * 128
                                                     + kb * 64 + g * 16));
                acc[n] = __builtin_amdgcn_mfma_f32_16x16x32_f16(vf, pf, acc[n], 0, 0, 0);
            }
        }
        __builtin_amdgcn_s_setprio(0);
        __syncthreads();
    }

    // epilogue: reduce l across the 4 g-lanes (linear in all rescales), store
    l_r += __shfl_xor(l_r, 16);
    l_r += __shfl_xor(l_r, 32);
    const float inv = 1.f / l_r;
    const int q = q0 + ql;
    f16* orow = Ob + ((size_t)bh * LL + q) * KDIM;
    #pragma unroll
    for (int n = 0; n < 4; ++n) {
        f16x4v o = {(f16)(acc[n][0] * inv), (f16)(acc[n][1] * inv),
                    (f16)(acc[n][2] * inv), (f16)(acc[n][3] * inv)};
        *(f16x4v*)(orow + n * 16 + g * 4) = o;
    }
}

// ---------------------------------------------------------------------------
extern "C" void kernel_launch(void* const* d_in, const int* in_sizes, int n_in,
                              void* d_out, int out_size, void* d_ws, size_t ws_size,
                              hipStream_t stream)
{
    const float* query = (const float*)d_in[0];
    const float* key   = (const float*)d_in[1];
    const float* value = (const float*)d_in[2];
    const int* wq = (const int*)d_in[3];
    const int* wk = (const int*)d_in[4];
    const int* wv = (const int*)d_in[5];
    const int* wo = (const int*)d_in[6];
    const float* bq = (const float*)d_in[7];
    const float* bk = (const float*)d_in[8];
    const float* bv = (const float*)d_in[9];
    const float* bo = (const float*)d_in[10];
    const float* scale_q = (const float*)d_in[11];
    const float* scale_k = (const float*)d_in[12];
    const float* scale_v = (const float*)d_in[13];
    const float* scale_o = (const float*)d_in[14];
    const float* zp_q = (const float*)d_in[15];
    const float* zp_k = (const float*)d_in[16];
    const float* zp_v = (const float*)d_in[17];
    const float* zp_o = (const float*)d_in[18];

    const size_t MD = (size_t)BB * LL * DD;       // 4.19M
    const size_t WT_SZ = (size_t)DD * DD;

    f16* Xq  = (f16*)d_ws;
    f16* Xk  = Xq + MD;
    f16* Xv  = Xk + MD;
    f16* WTq = Xv + MD;
    f16* WTk = WTq + WT_SZ;
    f16* WTv = WTk + WT_SZ;
    f16* WTo = WTv + WT_SZ;
    f16* Qh  = WTo + WT_SZ;
    f16* Kh  = Qh + MD;
    f16* VhT = Kh + MD;
    f16* Ob  = VhT + MD;   // [b][h][q][64]

    dim3 gprep(16, 16, 4);
    prep_all<<<gprep, 256, 0, stream>>>(wq, wk, wv, wo,
                                        scale_q, scale_k, scale_v, scale_o,
                                        zp_q, zp_k, zp_v, zp_o,
                                        WTq, WTk, WTv, WTo);

    dim3 gcast((unsigned)(MD / 4 / 256), 3);
    cast_all<<<gcast, 256, 0, stream>>>(query, key, value, Xq, Xk, Xv);

    dim3 gg(256, 1, 3);
    gemm_qkv<<<gg, 256, 0, stream>>>(Xq, Xk, Xv, WTq, WTk, WTv,
                                     bq, bk, bv, Qh, Kh, VhT);

    attn_f16<<<1024, 256, 0, stream>>>(Qh, Kh, VhT, Ob);

    gemm_out<<<256, 256, 0, stream>>>(Ob, WTo, bo, (float*)d_out);
}